// Round 19
// baseline (69.139 us; speedup 1.0000x reference)
//
#include <hip/hip_runtime.h>

#define L_LEN  1024
#define FDIM   16
#define PERIOD 24
#define HDIM   128
#define BATCH  1024
#define DDIM   (L_LEN*FDIM)      // 16384
#define NH3    (3*HDIM)          // 384
#define THALF  12
#define NCLS   10
#define FH     (FDIM*HDIM)       // 2048
#define NLB    16                // l-strip per build_wp block
#define PCHUNK 4                 // phase_sums l-chunks
#define NSLOT  48                // 24 interior phases + 24 edge l's

typedef short bf16x8  __attribute__((ext_vector_type(8)));
typedef short bf16x16 __attribute__((ext_vector_type(16)));
typedef float f32x4   __attribute__((ext_vector_type(4)));
typedef unsigned int u32x4 __attribute__((ext_vector_type(4)));

__device__ __forceinline__ unsigned short f2bf(float f) {
    unsigned int u = __float_as_uint(f);
    u += 0x7FFFu + ((u >> 16) & 1u);           // RNE
    return (unsigned short)(u >> 16);
}
__device__ __forceinline__ float cinv(int p) { return (p < 16) ? (1.0f/43.0f) : (1.0f/42.0f); }

// ---------------- kernel B1: partial per-phase column sums (4 l-chunks, 384 blocks) ----------------
__global__ void phase_sums_part(const float* __restrict__ We1, const float* __restrict__ We2,
                                float* __restrict__ u4) {
    int idx = blockIdx.x * blockDim.x + threadIdx.x;
    if (idx >= 2 * PERIOD * (FH / 4) * PCHUNK) return;
    int c    = idx / (2 * PERIOD * (FH / 4));
    int rem  = idx % (2 * PERIOD * (FH / 4));
    int w    = rem / (PERIOD * (FH / 4));
    int rem2 = rem % (PERIOD * (FH / 4));
    int p    = rem2 / (FH / 4);
    int fh4  = rem2 % (FH / 4);
    const float* W = w ? We2 : We1;
    int lbeg = c * (L_LEN / PCHUNK);
    int lend = lbeg + (L_LEN / PCHUNK);
    int l0   = lbeg + ((p - lbeg) % PERIOD + PERIOD) % PERIOD;
    f32x4 s = {0.f, 0.f, 0.f, 0.f};
    for (int l = l0; l < lend; l += PERIOD)
        s += *(const f32x4*)&W[(size_t)l * FH + fh4 * 4];
    *(f32x4*)&u4[(size_t)c * (2 * PERIOD * FH) + (size_t)w * PERIOD * FH + p * FH + fh4 * 4] = s;
}

// ---------------- kernel B2: fused 4-chunk reduce + slot tables (u eliminated) ----------------
// 16 blocks x 256 thr; block owns 32 fh4 columns. LDS stages reduced u for both mats,
// then all 48 slots are computed from LDS.
__global__ void phase_tables(const float* __restrict__ u4, float* __restrict__ t1,
                             float* __restrict__ t2) {
    __shared__ f32x4 ul[2][PERIOD][32];   // 24 KB
    int fb  = blockIdx.x * 32;            // fh4 base
    int tid = threadIdx.x;

    for (int e = tid; e < 2 * PERIOD * 32; e += 256) {
        int w  = e / (PERIOD * 32);
        int p  = (e / 32) % PERIOD;
        int f4 = e % 32;
        size_t base = (size_t)w * PERIOD * FH + (size_t)p * FH + (size_t)(fb + f4) * 4;
        f32x4 s = *(const f32x4*)&u4[base];
        #pragma unroll
        for (int c = 1; c < PCHUNK; ++c)
            s += *(const f32x4*)&u4[(size_t)c * (2 * PERIOD * FH) + base];
        ul[w][p][f4] = s;
    }
    __syncthreads();

    const float inv25 = 1.0f / 25.0f;
    for (int e = tid; e < NSLOT * 32; e += 256) {
        int s  = e / 32;
        int f4 = e % 32;
        f32x4 v1, v2;
        f32x4 mav1 = {0.f, 0.f, 0.f, 0.f}, mav2 = {0.f, 0.f, 0.f, 0.f};
        if (s < PERIOD) {                              // interior phase
            int p = s, pr = (p + THALF) % PERIOD;
            f32x4 Sv1 = {0.f, 0.f, 0.f, 0.f}, Sv2 = {0.f, 0.f, 0.f, 0.f};
            #pragma unroll
            for (int q = 0; q < PERIOD; ++q) {
                float cq = cinv(q);
                Sv1 += ul[0][q][f4] * cq;
                Sv2 += ul[1][q][f4] * cq;
            }
            v1 = ul[0][p][f4] * cinv(p);
            v2 = ul[1][p][f4] * cinv(p);
            mav1 = (Sv1 + ul[0][pr][f4] * cinv(pr)) * inv25;
            mav2 = (Sv2 + ul[1][pr][f4] * cinv(pr)) * inv25;
        } else {                                       // edge l, exact clipped window
            int e2 = s - PERIOD;
            int l  = (e2 < THALF) ? e2 : (L_LEN - THALF + (e2 - THALF));
            int pl = l % PERIOD;
            v1 = ul[0][pl][f4] * cinv(pl);
            v2 = ul[1][pl][f4] * cinv(pl);
            #pragma unroll
            for (int dl = -THALF; dl <= THALF; ++dl) {
                int j = l + dl;
                if (j >= 0 && j < L_LEN) {
                    int p = j % PERIOD;
                    float ci = cinv(p);
                    mav1 += ul[0][p][f4] * ci;
                    mav2 += ul[1][p][f4] * ci;
                }
            }
            mav1 *= inv25; mav2 *= inv25;
        }
        *(f32x4*)&t1[(size_t)s * FH + (size_t)(fb + f4) * 4] = v1 - mav1;
        *(f32x4*)&t2[(size_t)s * FH + (size_t)(fb + f4) * 4] = mav2 - v2;
    }
}

// ---------------- kernel C: build W' (bf16) — NLB=16, window regs + table lookups ----------------
__launch_bounds__(256, 2)
__global__ void build_wp(const float* __restrict__ We0, const float* __restrict__ We2,
                         const float* __restrict__ t1, const float* __restrict__ t2,
                         unsigned short* __restrict__ Wp) {
    __shared__ unsigned short tile[3][NLB][16][18];   // 27.6 KB
    int f  = threadIdx.x >> 4;
    int hl = threadIdx.x & 15;
    int h  = blockIdx.x * 16 + hl;
    int l0 = blockIdx.y * NLB;
    int fh = f * HDIM + h;

    float w0[NLB + 25], w2[NLB + 25];                 // 41 regs each
    #pragma unroll
    for (int i = 0; i < NLB + 25; ++i) {
        int j = l0 - THALF + i;
        if (j >= 0 && j < L_LEN) {
            w0[i] = We0[(size_t)j * FH + fh];
            w2[i] = We2[(size_t)j * FH + fh];
        } else { w0[i] = 0.f; w2[i] = 0.f; }
    }

    float s0 = 0.f, s2 = 0.f;
    #pragma unroll
    for (int i = 0; i < 25; ++i) { s0 += w0[i]; s2 += w2[i]; }

    const float inv25 = 1.0f / 25.0f;
    #pragma unroll
    for (int r = 0; r < NLB; ++r) {
        int l = l0 + r;
        int slot = (l >= THALF && l < L_LEN - THALF)
                 ? (l % PERIOD)
                 : (PERIOD + ((l < THALF) ? l : (THALF + (l - (L_LEN - THALF)))));
        float tt1 = t1[(size_t)slot * FH + fh];
        float tt2 = t2[(size_t)slot * FH + fh];

        float out0 = s0 * inv25;                        // (T We0)[l]
        float out1 = tt1;                               // S^T We1
        float out2 = w2[r + THALF] - s2 * inv25 + tt2;  // (I-T-S)^T We2

        tile[0][r][hl][f] = f2bf(out0);
        tile[1][r][hl][f] = f2bf(out1);
        tile[2][r][hl][f] = f2bf(out2);

        s0 += w0[r + 25] - w0[r];                       // register-only slide
        s2 += w2[r + 25] - w2[r];
    }
    __syncthreads();

    {
        int cid = threadIdx.x;
        #pragma unroll
        for (int pass = 0; pass < 3; ++pass, cid += 256) {   // 3*16*16 = 768 chunks
            if (cid < 3 * 16 * NLB) {
                int m  = cid / (16 * NLB);
                int rm = cid % (16 * NLB);
                int h2 = rm / NLB;
                int ll = rm % NLB;
                const unsigned int* src = (const unsigned int*)&tile[m][ll][h2][0];
                union { unsigned int d[8]; bf16x16 v; } cvt;
                #pragma unroll
                for (int i = 0; i < 8; ++i) cvt.d[i] = src[i];
                *(bf16x16*)&Wp[(size_t)(m * HDIM + blockIdx.x * 16 + h2) * DDIM
                               + (size_t)(l0 + ll) * FDIM] = cvt.v;
            }
        }
    }
}

// ---------------- kernel D: part[z] = x @ Wp^T — BN=192 champion (frozen) ----------------
#define GBM 64
#define GBN 192
#define GBK 64
#define GSPLIT 16
#define GKSPL (DDIM / GSPLIT)    // 1024
#define GKST  (GKSPL / GBK)      // 16
#define LDA   72                 // A LDS stride: 144B ≡ 4 dwords mod 32 -> 2-way (free)
#define NWG2  (16 * 2 * GSPLIT)  // 512 blocks, %8==0 (bijective XCD swizzle)

__launch_bounds__(256, 2)
__global__ void gemm3(const float* __restrict__ x, const unsigned short* __restrict__ Wp,
                      float* __restrict__ part) {
    __shared__ unsigned short As[2][GBM * LDA];   // 2 x 9.2 KB
    __shared__ unsigned short Bs[2][GBN * GBK];   // 2 x 24 KB, linear dest, swizzled content
    int bid = blockIdx.x;
    int swz = (bid & 7) * (NWG2 / 8) + (bid >> 3);
    int bz  = swz / 32;            // 0..15
    int rem = swz % 32;
    int by  = rem / 16;            // 0..1
    int bx  = rem % 16;            // 0..15
    int m0 = bx * GBM, n0 = by * GBN, k0 = bz * GKSPL;
    int tid = threadIdx.x, lane = tid & 63, wave = tid >> 6;
    int wn = wave;                 // 4 waves: 1m x 4n, wave tile 64 x 48

    int arow = tid >> 2, aseg = tid & 3;
    const float* ag = x + (size_t)(m0 + arow) * DDIM + k0 + aseg * 16;
    int brc  = lane >> 3;                       // row within 8-row chunk
    int bsg  = (lane & 7) ^ brc;                // T2 source-pre-swizzle

    f32x4 Ra[4], Rb[4];
    f32x4 acc[4][3] = {};

    auto aload = [&](f32x4* R, int s) {
        const float* a = ag + s * GBK;
        #pragma unroll
        for (int i = 0; i < 4; ++i) R[i] = *(const f32x4*)(a + 4 * i);
    };
    auto astore = [&](const f32x4* R, int buf) {
        unsigned int w[8];
        #pragma unroll
        for (int t = 0; t < 8; ++t) {
            float lo = R[t >> 1][(t & 1) * 2];
            float hi = R[t >> 1][(t & 1) * 2 + 1];
            asm("v_cvt_pk_bf16_f32 %0, %1, %2" : "=v"(w[t]) : "v"(lo), "v"(hi));
        }
        unsigned short* dst = &As[buf][arow * LDA + aseg * 16];
        u32x4 v0 = {w[0], w[1], w[2], w[3]};
        u32x4 v1 = {w[4], w[5], w[6], w[7]};
        *(u32x4*)dst       = v0;
        *(u32x4*)(dst + 8) = v1;
    };
    auto bstage = [&](int buf, int s) {
        #pragma unroll
        for (int q = 0; q < 6; ++q) {
            int c = wave * 6 + q;                  // 8-row chunk id (0..23) -> 192 rows
            const unsigned short* g = Wp + (size_t)(n0 + c * 8 + brc) * DDIM
                                        + k0 + s * GBK + bsg * 8;
            __builtin_amdgcn_global_load_lds(
                (const __attribute__((address_space(1))) void*)g,
                (__attribute__((address_space(3))) void*)&Bs[buf][c * 512], 16, 0, 0);
        }
    };
    int frow = lane & 15, hi4 = lane >> 4;
    auto compute = [&](int buf) {
        #pragma unroll
        for (int ks = 0; ks < 2; ++ks) {
            bf16x8 av[4], bv[3];
            #pragma unroll
            for (int i = 0; i < 4; ++i)
                av[i] = *(const bf16x8*)&As[buf][(i*16 + frow) * LDA + ks*32 + hi4*8];
            #pragma unroll
            for (int j = 0; j < 3; ++j) {
                int rB = wn*48 + j*16 + frow;
                int sL = (ks*4 + hi4) ^ (frow & 7);    // un-swizzle on read
                bv[j] = *(const bf16x8*)&Bs[buf][rB * GBK + sL * 8];
            }
            #pragma unroll
            for (int i = 0; i < 4; ++i)
                #pragma unroll
                for (int j = 0; j < 3; ++j)
                    acc[i][j] = __builtin_amdgcn_mfma_f32_16x16x32_bf16(av[i], bv[j], acc[i][j], 0, 0, 0);
        }
    };

    // prologue: regs k0,k1; B0 DMA; A0 in LDS; barrier drains all
    aload(Ra, 0); aload(Rb, 1); bstage(0, 0); astore(Ra, 0);
    __syncthreads();

    for (int s2 = 0; s2 < GKST; s2 += 2) {
        {   int s = s2;                                  // even step, bufs 0
            if (s + 1 < GKST) bstage(1, s + 1);
            if (s + 2 < GKST) aload(Ra, s + 2);
            if (s + 1 < GKST) astore(Rb, 1);
            compute(0);
            __syncthreads();
        }
        {   int s = s2 + 1;                              // odd step, bufs 1
            if (s + 1 < GKST) bstage(0, s + 1);
            if (s + 2 < GKST) aload(Rb, s + 2);
            if (s + 1 < GKST) astore(Ra, 0);
            compute(1);
            __syncthreads();
        }
    }

    // epilogue: plain streaming stores to this k-split's private slab (no atomics)
    float* pslab = part + (size_t)bz * (BATCH * NH3);
    int orow = (lane >> 4) * 4, ocol = lane & 15;   // C/D: col=lane&15, row=(lane>>4)*4+r
    #pragma unroll
    for (int i = 0; i < 4; ++i)
        #pragma unroll
        for (int j = 0; j < 3; ++j)
            #pragma unroll
            for (int r = 0; r < 4; ++r)
                pslab[(size_t)(m0 + i*16 + orow + r) * NH3
                      + (n0 + wn*48 + j*16 + ocol)] = acc[i][j][r];
}

// ---------------- kernel E: fused MLP tail — 4 batch rows per block (frozen) ----------------
__launch_bounds__(1024, 2)
__global__ void mlp_fused2(const float* __restrict__ part, const float* __restrict__ be0,
                           const float* __restrict__ be1, const float* __restrict__ be2,
                           const float* __restrict__ Wf1, const float* __restrict__ bf1,
                           const float* __restrict__ Wf2, const float* __restrict__ bf2,
                           float* __restrict__ out) {
    __shared__ float fr[4][NH3];        // 6 KB
    __shared__ float hp[8][4][HDIM];    // 16 KB
    __shared__ float hs[4][HDIM];       // 2 KB
    int b0 = blockIdx.x * 4, tid = threadIdx.x;

    for (int e = tid; e < 4 * NH3; e += 1024) {       // slab-reduce 4 rows
        int rr = e / NH3, cc = e % NH3;
        float v = (cc < HDIM) ? be0[cc]
                : (cc < 2*HDIM ? be1[cc - HDIM] : be2[cc - 2*HDIM]);
        #pragma unroll
        for (int z = 0; z < GSPLIT; ++z)              // 16 independent loads
            v += part[(size_t)z * (BATCH * NH3) + (size_t)(b0 + rr) * NH3 + cc];
        fr[rr][cc] = v;
    }
    __syncthreads();

    int j = tid & 127, c = tid >> 7;                  // c = 0..7, 48 i's each
    int i0 = c * 48;
    float a0 = 0.f, a1 = 0.f, a2 = 0.f, a3 = 0.f;     // 4 independent chains of 48
    #pragma unroll
    for (int k = 0; k < 48; ++k) {
        float w = Wf1[(size_t)(i0 + k) * HDIM + j];   // ONE load, FOUR fmas
        float f0 = fr[0][i0 + k], f1 = fr[1][i0 + k];
        float f2 = fr[2][i0 + k], f3 = fr[3][i0 + k];
        a0 = fmaf(f0, w, a0);
        a1 = fmaf(f1, w, a1);
        a2 = fmaf(f2, w, a2);
        a3 = fmaf(f3, w, a3);
    }
    hp[c][0][j] = a0; hp[c][1][j] = a1; hp[c][2][j] = a2; hp[c][3][j] = a3;
    __syncthreads();

    if (tid < 4 * HDIM) {
        int rr = tid >> 7, jj = tid & 127;
        float v = bf1[jj];
        #pragma unroll
        for (int cc = 0; cc < 8; ++cc) v += hp[cc][rr][jj];
        hs[rr][jj] = fmaxf(v, 0.f);
    }
    __syncthreads();

    int lane = tid & 63, wave = tid >> 6;             // 16 waves
    int rr = wave & 3, base = wave >> 2;              // wave -> (row, class-stride-4 set)
    #pragma unroll
    for (int cc = base; cc < NCLS; cc += 4) {
        float pp = hs[rr][lane] * Wf2[(size_t)lane * NCLS + cc];
        pp = fmaf(hs[rr][lane + 64], Wf2[(size_t)(lane + 64) * NCLS + cc], pp);
        #pragma unroll
        for (int off = 32; off; off >>= 1) pp += __shfl_down(pp, off);
        if (lane == 0) out[(size_t)(b0 + rr) * NCLS + cc] = pp + bf2[cc];
    }
}

extern "C" void kernel_launch(void* const* d_in, const int* in_sizes, int n_in,
                              void* d_out, int out_size, void* d_ws, size_t ws_size,
                              hipStream_t stream) {
    const float* x   = (const float*)d_in[0];
    const float* We0 = (const float*)d_in[1];
    const float* be0 = (const float*)d_in[2];
    const float* We1 = (const float*)d_in[3];
    const float* be1 = (const float*)d_in[4];
    const float* We2 = (const float*)d_in[5];
    const float* be2 = (const float*)d_in[6];
    const float* Wf1 = (const float*)d_in[7];
    const float* bf1 = (const float*)d_in[8];
    const float* Wf2 = (const float*)d_in[9];
    const float* bf2 = (const float*)d_in[10];
    float* out = (float*)d_out;

    char* wsb = (char*)d_ws;
    size_t off = 0;
    unsigned short* Wp = (unsigned short*)(wsb + off); off += (size_t)NH3 * DDIM * sizeof(unsigned short);   // 12.6 MB
    float* u4   = (float*)(wsb + off); off += (size_t)PCHUNK * 2 * PERIOD * FH * sizeof(float);              // 1.57 MB
    float* t1   = (float*)(wsb + off); off += (size_t)NSLOT * FH * sizeof(float);                            // 0.39 MB
    float* t2   = (float*)(wsb + off); off += (size_t)NSLOT * FH * sizeof(float);                            // 0.39 MB
    float* part = (float*)(wsb + off); off += (size_t)GSPLIT * BATCH * NH3 * sizeof(float);                  // 25.2 MB

    phase_sums_part<<<(2 * PERIOD * (FH / 4) * PCHUNK + 255) / 256, 256, 0, stream>>>(We1, We2, u4);
    phase_tables<<<FH / 4 / 32, 256, 0, stream>>>(u4, t1, t2);
    build_wp<<<dim3(8, L_LEN / NLB), 256, 0, stream>>>(We0, We2, t1, t2, Wp);
    gemm3<<<NWG2, 256, 0, stream>>>(x, Wp, part);
    mlp_fused2<<<BATCH / 4, 1024, 0, stream>>>(part, be0, be1, be2, Wf1, bf1, Wf2, bf2, out);
}

// Round 20
// 62.724 us; speedup vs baseline: 1.1023x; 1.1023x over previous
//
#include <hip/hip_runtime.h>

#define L_LEN  1024
#define FDIM   16
#define PERIOD 24
#define HDIM   128
#define BATCH  1024
#define DDIM   (L_LEN*FDIM)      // 16384
#define NH3    (3*HDIM)          // 384
#define THALF  12
#define NCLS   10
#define FH     (FDIM*HDIM)       // 2048
#define NLB    8                 // l-strip per build_wp block
#define PCHUNK 4                 // phase_sums l-chunks
#define NSLOT  48                // 24 interior phases + 24 edge l's
#define TBF4   8                 // fh4 columns per phase_tables block

typedef short bf16x8  __attribute__((ext_vector_type(8)));
typedef short bf16x16 __attribute__((ext_vector_type(16)));
typedef float f32x4   __attribute__((ext_vector_type(4)));
typedef unsigned int u32x4 __attribute__((ext_vector_type(4)));

__device__ __forceinline__ unsigned short f2bf(float f) {
    unsigned int u = __float_as_uint(f);
    u += 0x7FFFu + ((u >> 16) & 1u);           // RNE
    return (unsigned short)(u >> 16);
}
__device__ __forceinline__ float cinv(int p) { return (p < 16) ? (1.0f/43.0f) : (1.0f/42.0f); }

// ---------------- kernel B1: partial per-phase column sums (4 l-chunks, 384 blocks) ----------------
__global__ void phase_sums_part(const float* __restrict__ We1, const float* __restrict__ We2,
                                float* __restrict__ u4) {
    int idx = blockIdx.x * blockDim.x + threadIdx.x;
    if (idx >= 2 * PERIOD * (FH / 4) * PCHUNK) return;
    int c    = idx / (2 * PERIOD * (FH / 4));
    int rem  = idx % (2 * PERIOD * (FH / 4));
    int w    = rem / (PERIOD * (FH / 4));
    int rem2 = rem % (PERIOD * (FH / 4));
    int p    = rem2 / (FH / 4);
    int fh4  = rem2 % (FH / 4);
    const float* W = w ? We2 : We1;
    int lbeg = c * (L_LEN / PCHUNK);
    int lend = lbeg + (L_LEN / PCHUNK);
    int l0   = lbeg + ((p - lbeg) % PERIOD + PERIOD) % PERIOD;
    f32x4 s = {0.f, 0.f, 0.f, 0.f};
    for (int l = l0; l < lend; l += PERIOD)
        s += *(const f32x4*)&W[(size_t)l * FH + fh4 * 4];
    *(f32x4*)&u4[(size_t)c * (2 * PERIOD * FH) + (size_t)w * PERIOD * FH + p * FH + fh4 * 4] = s;
}

// ---------------- kernel B2: fused 4-chunk reduce + slot tables (64 blocks) ----------------
__global__ void phase_tables(const float* __restrict__ u4, float* __restrict__ t1,
                             float* __restrict__ t2) {
    __shared__ f32x4 ul[2][PERIOD][TBF4];   // 6 KB
    int fb  = blockIdx.x * TBF4;            // fh4 base
    int tid = threadIdx.x;

    for (int e = tid; e < 2 * PERIOD * TBF4; e += 256) {
        int w  = e / (PERIOD * TBF4);
        int p  = (e / TBF4) % PERIOD;
        int f4 = e % TBF4;
        size_t base = (size_t)w * PERIOD * FH + (size_t)p * FH + (size_t)(fb + f4) * 4;
        f32x4 s = *(const f32x4*)&u4[base];
        #pragma unroll
        for (int c = 1; c < PCHUNK; ++c)
            s += *(const f32x4*)&u4[(size_t)c * (2 * PERIOD * FH) + base];
        ul[w][p][f4] = s;
    }
    __syncthreads();

    const float inv25 = 1.0f / 25.0f;
    for (int e = tid; e < NSLOT * TBF4; e += 256) {
        int s  = e / TBF4;
        int f4 = e % TBF4;
        f32x4 v1, v2;
        f32x4 mav1 = {0.f, 0.f, 0.f, 0.f}, mav2 = {0.f, 0.f, 0.f, 0.f};
        if (s < PERIOD) {                              // interior phase
            int p = s, pr = (p + THALF) % PERIOD;
            f32x4 Sv1 = {0.f, 0.f, 0.f, 0.f}, Sv2 = {0.f, 0.f, 0.f, 0.f};
            #pragma unroll
            for (int q = 0; q < PERIOD; ++q) {
                float cq = cinv(q);
                Sv1 += ul[0][q][f4] * cq;
                Sv2 += ul[1][q][f4] * cq;
            }
            v1 = ul[0][p][f4] * cinv(p);
            v2 = ul[1][p][f4] * cinv(p);
            mav1 = (Sv1 + ul[0][pr][f4] * cinv(pr)) * inv25;
            mav2 = (Sv2 + ul[1][pr][f4] * cinv(pr)) * inv25;
        } else {                                       // edge l, exact clipped window
            int e2 = s - PERIOD;
            int l  = (e2 < THALF) ? e2 : (L_LEN - THALF + (e2 - THALF));
            int pl = l % PERIOD;
            v1 = ul[0][pl][f4] * cinv(pl);
            v2 = ul[1][pl][f4] * cinv(pl);
            #pragma unroll
            for (int dl = -THALF; dl <= THALF; ++dl) {
                int j = l + dl;
                if (j >= 0 && j < L_LEN) {
                    int p = j % PERIOD;
                    float ci = cinv(p);
                    mav1 += ul[0][p][f4] * ci;
                    mav2 += ul[1][p][f4] * ci;
                }
            }
            mav1 *= inv25; mav2 *= inv25;
        }
        *(f32x4*)&t1[(size_t)s * FH + (size_t)(fb + f4) * 4] = v1 - mav1;
        *(f32x4*)&t2[(size_t)s * FH + (size_t)(fb + f4) * 4] = mav2 - v2;
    }
}

// ---------------- kernel C: build W' (bf16) — NLB=8, window regs + table lookups ----------------
__launch_bounds__(256, 3)
__global__ void build_wp(const float* __restrict__ We0, const float* __restrict__ We2,
                         const float* __restrict__ t1, const float* __restrict__ t2,
                         unsigned short* __restrict__ Wp) {
    __shared__ unsigned short tile[3][NLB][16][18];   // 13.8 KB
    int f  = threadIdx.x >> 4;
    int hl = threadIdx.x & 15;
    int h  = blockIdx.x * 16 + hl;
    int l0 = blockIdx.y * NLB;
    int fh = f * HDIM + h;

    float w0[NLB + 25], w2[NLB + 25];
    #pragma unroll
    for (int i = 0; i < NLB + 25; ++i) {
        int j = l0 - THALF + i;
        if (j >= 0 && j < L_LEN) {
            w0[i] = We0[(size_t)j * FH + fh];
            w2[i] = We2[(size_t)j * FH + fh];
        } else { w0[i] = 0.f; w2[i] = 0.f; }
    }

    float s0 = 0.f, s2 = 0.f;
    #pragma unroll
    for (int i = 0; i < 25; ++i) { s0 += w0[i]; s2 += w2[i]; }

    const float inv25 = 1.0f / 25.0f;
    #pragma unroll
    for (int r = 0; r < NLB; ++r) {
        int l = l0 + r;
        int slot = (l >= THALF && l < L_LEN - THALF)
                 ? (l % PERIOD)
                 : (PERIOD + ((l < THALF) ? l : (THALF + (l - (L_LEN - THALF)))));
        float tt1 = t1[(size_t)slot * FH + fh];
        float tt2 = t2[(size_t)slot * FH + fh];

        float out0 = s0 * inv25;                        // (T We0)[l]
        float out1 = tt1;                               // S^T We1
        float out2 = w2[r + THALF] - s2 * inv25 + tt2;  // (I-T-S)^T We2

        tile[0][r][hl][f] = f2bf(out0);
        tile[1][r][hl][f] = f2bf(out1);
        tile[2][r][hl][f] = f2bf(out2);

        s0 += w0[r + 25] - w0[r];                       // register-only slide
        s2 += w2[r + 25] - w2[r];
    }
    __syncthreads();

    {
        int cid = threadIdx.x;
        #pragma unroll
        for (int pass = 0; pass < 2; ++pass, cid += 256) {
            if (cid < 3 * 16 * NLB) {
                int m  = cid / (16 * NLB);
                int rm = cid % (16 * NLB);
                int h2 = rm / NLB;
                int ll = rm % NLB;
                const unsigned int* src = (const unsigned int*)&tile[m][ll][h2][0];
                union { unsigned int d[8]; bf16x16 v; } cvt;
                #pragma unroll
                for (int i = 0; i < 8; ++i) cvt.d[i] = src[i];
                *(bf16x16*)&Wp[(size_t)(m * HDIM + blockIdx.x * 16 + h2) * DDIM
                               + (size_t)(l0 + ll) * FDIM] = cvt.v;
            }
        }
    }
}

// ---------------- kernel D: part[z] = x @ Wp^T — BN=192 champion (frozen) ----------------
#define GBM 64
#define GBN 192
#define GBK 64
#define GSPLIT 16
#define GKSPL (DDIM / GSPLIT)    // 1024
#define GKST  (GKSPL / GBK)      // 16
#define LDA   72                 // A LDS stride: 144B ≡ 4 dwords mod 32 -> 2-way (free)
#define NWG2  (16 * 2 * GSPLIT)  // 512 blocks, %8==0 (bijective XCD swizzle)

__launch_bounds__(256, 2)
__global__ void gemm3(const float* __restrict__ x, const unsigned short* __restrict__ Wp,
                      float* __restrict__ part) {
    __shared__ unsigned short As[2][GBM * LDA];   // 2 x 9.2 KB
    __shared__ unsigned short Bs[2][GBN * GBK];   // 2 x 24 KB, linear dest, swizzled content
    int bid = blockIdx.x;
    int swz = (bid & 7) * (NWG2 / 8) + (bid >> 3);
    int bz  = swz / 32;            // 0..15
    int rem = swz % 32;
    int by  = rem / 16;            // 0..1
    int bx  = rem % 16;            // 0..15
    int m0 = bx * GBM, n0 = by * GBN, k0 = bz * GKSPL;
    int tid = threadIdx.x, lane = tid & 63, wave = tid >> 6;
    int wn = wave;                 // 4 waves: 1m x 4n, wave tile 64 x 48

    int arow = tid >> 2, aseg = tid & 3;
    const float* ag = x + (size_t)(m0 + arow) * DDIM + k0 + aseg * 16;
    int brc  = lane >> 3;                       // row within 8-row chunk
    int bsg  = (lane & 7) ^ brc;                // T2 source-pre-swizzle

    f32x4 Ra[4], Rb[4];
    f32x4 acc[4][3] = {};

    auto aload = [&](f32x4* R, int s) {
        const float* a = ag + s * GBK;
        #pragma unroll
        for (int i = 0; i < 4; ++i) R[i] = *(const f32x4*)(a + 4 * i);
    };
    auto astore = [&](const f32x4* R, int buf) {
        unsigned int w[8];
        #pragma unroll
        for (int t = 0; t < 8; ++t) {
            float lo = R[t >> 1][(t & 1) * 2];
            float hi = R[t >> 1][(t & 1) * 2 + 1];
            asm("v_cvt_pk_bf16_f32 %0, %1, %2" : "=v"(w[t]) : "v"(lo), "v"(hi));
        }
        unsigned short* dst = &As[buf][arow * LDA + aseg * 16];
        u32x4 v0 = {w[0], w[1], w[2], w[3]};
        u32x4 v1 = {w[4], w[5], w[6], w[7]};
        *(u32x4*)dst       = v0;
        *(u32x4*)(dst + 8) = v1;
    };
    auto bstage = [&](int buf, int s) {
        #pragma unroll
        for (int q = 0; q < 6; ++q) {
            int c = wave * 6 + q;                  // 8-row chunk id (0..23) -> 192 rows
            const unsigned short* g = Wp + (size_t)(n0 + c * 8 + brc) * DDIM
                                        + k0 + s * GBK + bsg * 8;
            __builtin_amdgcn_global_load_lds(
                (const __attribute__((address_space(1))) void*)g,
                (__attribute__((address_space(3))) void*)&Bs[buf][c * 512], 16, 0, 0);
        }
    };
    int frow = lane & 15, hi4 = lane >> 4;
    auto compute = [&](int buf) {
        #pragma unroll
        for (int ks = 0; ks < 2; ++ks) {
            bf16x8 av[4], bv[3];
            #pragma unroll
            for (int i = 0; i < 4; ++i)
                av[i] = *(const bf16x8*)&As[buf][(i*16 + frow) * LDA + ks*32 + hi4*8];
            #pragma unroll
            for (int j = 0; j < 3; ++j) {
                int rB = wn*48 + j*16 + frow;
                int sL = (ks*4 + hi4) ^ (frow & 7);    // un-swizzle on read
                bv[j] = *(const bf16x8*)&Bs[buf][rB * GBK + sL * 8];
            }
            #pragma unroll
            for (int i = 0; i < 4; ++i)
                #pragma unroll
                for (int j = 0; j < 3; ++j)
                    acc[i][j] = __builtin_amdgcn_mfma_f32_16x16x32_bf16(av[i], bv[j], acc[i][j], 0, 0, 0);
        }
    };

    // prologue: regs k0,k1; B0 DMA; A0 in LDS; barrier drains all
    aload(Ra, 0); aload(Rb, 1); bstage(0, 0); astore(Ra, 0);
    __syncthreads();

    for (int s2 = 0; s2 < GKST; s2 += 2) {
        {   int s = s2;                                  // even step, bufs 0
            if (s + 1 < GKST) bstage(1, s + 1);
            if (s + 2 < GKST) aload(Ra, s + 2);
            if (s + 1 < GKST) astore(Rb, 1);
            compute(0);
            __syncthreads();
        }
        {   int s = s2 + 1;                              // odd step, bufs 1
            if (s + 1 < GKST) bstage(0, s + 1);
            if (s + 2 < GKST) aload(Rb, s + 2);
            if (s + 1 < GKST) astore(Ra, 0);
            compute(1);
            __syncthreads();
        }
    }

    // epilogue: plain streaming stores to this k-split's private slab (no atomics)
    float* pslab = part + (size_t)bz * (BATCH * NH3);
    int orow = (lane >> 4) * 4, ocol = lane & 15;   // C/D: col=lane&15, row=(lane>>4)*4+r
    #pragma unroll
    for (int i = 0; i < 4; ++i)
        #pragma unroll
        for (int j = 0; j < 3; ++j)
            #pragma unroll
            for (int r = 0; r < 4; ++r)
                pslab[(size_t)(m0 + i*16 + orow + r) * NH3
                      + (n0 + wn*48 + j*16 + ocol)] = acc[i][j][r];
}

// ---------------- kernel E: fused MLP tail — 4 batch rows per block (frozen) ----------------
__launch_bounds__(1024, 2)
__global__ void mlp_fused2(const float* __restrict__ part, const float* __restrict__ be0,
                           const float* __restrict__ be1, const float* __restrict__ be2,
                           const float* __restrict__ Wf1, const float* __restrict__ bf1,
                           const float* __restrict__ Wf2, const float* __restrict__ bf2,
                           float* __restrict__ out) {
    __shared__ float fr[4][NH3];        // 6 KB
    __shared__ float hp[8][4][HDIM];    // 16 KB
    __shared__ float hs[4][HDIM];       // 2 KB
    int b0 = blockIdx.x * 4, tid = threadIdx.x;

    for (int e = tid; e < 4 * NH3; e += 1024) {       // slab-reduce 4 rows
        int rr = e / NH3, cc = e % NH3;
        float v = (cc < HDIM) ? be0[cc]
                : (cc < 2*HDIM ? be1[cc - HDIM] : be2[cc - 2*HDIM]);
        #pragma unroll
        for (int z = 0; z < GSPLIT; ++z)              // 16 independent loads
            v += part[(size_t)z * (BATCH * NH3) + (size_t)(b0 + rr) * NH3 + cc];
        fr[rr][cc] = v;
    }
    __syncthreads();

    int j = tid & 127, c = tid >> 7;                  // c = 0..7, 48 i's each
    int i0 = c * 48;
    float a0 = 0.f, a1 = 0.f, a2 = 0.f, a3 = 0.f;     // 4 independent chains of 48
    #pragma unroll
    for (int k = 0; k < 48; ++k) {
        float w = Wf1[(size_t)(i0 + k) * HDIM + j];   // ONE load, FOUR fmas
        float f0 = fr[0][i0 + k], f1 = fr[1][i0 + k];
        float f2 = fr[2][i0 + k], f3 = fr[3][i0 + k];
        a0 = fmaf(f0, w, a0);
        a1 = fmaf(f1, w, a1);
        a2 = fmaf(f2, w, a2);
        a3 = fmaf(f3, w, a3);
    }
    hp[c][0][j] = a0; hp[c][1][j] = a1; hp[c][2][j] = a2; hp[c][3][j] = a3;
    __syncthreads();

    if (tid < 4 * HDIM) {
        int rr = tid >> 7, jj = tid & 127;
        float v = bf1[jj];
        #pragma unroll
        for (int cc = 0; cc < 8; ++cc) v += hp[cc][rr][jj];
        hs[rr][jj] = fmaxf(v, 0.f);
    }
    __syncthreads();

    int lane = tid & 63, wave = tid >> 6;             // 16 waves
    int rr = wave & 3, base = wave >> 2;              // wave -> (row, class-stride-4 set)
    #pragma unroll
    for (int cc = base; cc < NCLS; cc += 4) {
        float pp = hs[rr][lane] * Wf2[(size_t)lane * NCLS + cc];
        pp = fmaf(hs[rr][lane + 64], Wf2[(size_t)(lane + 64) * NCLS + cc], pp);
        #pragma unroll
        for (int off = 32; off; off >>= 1) pp += __shfl_down(pp, off);
        if (lane == 0) out[(size_t)(b0 + rr) * NCLS + cc] = pp + bf2[cc];
    }
}

extern "C" void kernel_launch(void* const* d_in, const int* in_sizes, int n_in,
                              void* d_out, int out_size, void* d_ws, size_t ws_size,
                              hipStream_t stream) {
    const float* x   = (const float*)d_in[0];
    const float* We0 = (const float*)d_in[1];
    const float* be0 = (const float*)d_in[2];
    const float* We1 = (const float*)d_in[3];
    const float* be1 = (const float*)d_in[4];
    const float* We2 = (const float*)d_in[5];
    const float* be2 = (const float*)d_in[6];
    const float* Wf1 = (const float*)d_in[7];
    const float* bf1 = (const float*)d_in[8];
    const float* Wf2 = (const float*)d_in[9];
    const float* bf2 = (const float*)d_in[10];
    float* out = (float*)d_out;

    char* wsb = (char*)d_ws;
    size_t off = 0;
    unsigned short* Wp = (unsigned short*)(wsb + off); off += (size_t)NH3 * DDIM * sizeof(unsigned short);   // 12.6 MB
    float* u4   = (float*)(wsb + off); off += (size_t)PCHUNK * 2 * PERIOD * FH * sizeof(float);              // 1.57 MB
    float* t1   = (float*)(wsb + off); off += (size_t)NSLOT * FH * sizeof(float);                            // 0.39 MB
    float* t2   = (float*)(wsb + off); off += (size_t)NSLOT * FH * sizeof(float);                            // 0.39 MB
    float* part = (float*)(wsb + off); off += (size_t)GSPLIT * BATCH * NH3 * sizeof(float);                  // 25.2 MB

    phase_sums_part<<<(2 * PERIOD * (FH / 4) * PCHUNK + 255) / 256, 256, 0, stream>>>(We1, We2, u4);
    phase_tables<<<(FH / 4) / TBF4, 256, 0, stream>>>(u4, t1, t2);
    build_wp<<<dim3(8, L_LEN / NLB), 256, 0, stream>>>(We0, We2, t1, t2, Wp);
    gemm3<<<NWG2, 256, 0, stream>>>(x, Wp, part);
    mlp_fused2<<<BATCH / 4, 1024, 0, stream>>>(part, be0, be1, be2, Wf1, bf1, Wf2, bf2, out);
}

// Round 21
// 60.326 us; speedup vs baseline: 1.1461x; 1.0397x over previous
//
#include <hip/hip_runtime.h>

#define L_LEN  1024
#define FDIM   16
#define PERIOD 24
#define HDIM   128
#define BATCH  1024
#define DDIM   (L_LEN*FDIM)      // 16384
#define NH3    (3*HDIM)          // 384
#define THALF  12
#define NCLS   10
#define FH     (FDIM*HDIM)       // 2048
#define NLB    8                 // l-strip per build_wp block
#define PCHUNK 4                 // phase_sums l-chunks
#define NSLOT  48                // 24 interior phases + 24 edge l's
#define TBF4   8                 // fh4 columns per phase_tables block

typedef short bf16x8  __attribute__((ext_vector_type(8)));
typedef short bf16x16 __attribute__((ext_vector_type(16)));
typedef float f32x4   __attribute__((ext_vector_type(4)));
typedef unsigned int u32x4 __attribute__((ext_vector_type(4)));

__device__ __forceinline__ unsigned short f2bf(float f) {
    unsigned int u = __float_as_uint(f);
    u += 0x7FFFu + ((u >> 16) & 1u);           // RNE
    return (unsigned short)(u >> 16);
}
__device__ __forceinline__ float bf2f(unsigned short u) {
    return __uint_as_float((unsigned int)u << 16);
}
__device__ __forceinline__ float cinv(int p) { return (p < 16) ? (1.0f/43.0f) : (1.0f/42.0f); }

// ---------------- kernel B1: partial per-phase column sums (4 l-chunks, 384 blocks) ----------------
__global__ void phase_sums_part(const float* __restrict__ We1, const float* __restrict__ We2,
                                float* __restrict__ u4) {
    int idx = blockIdx.x * blockDim.x + threadIdx.x;
    if (idx >= 2 * PERIOD * (FH / 4) * PCHUNK) return;
    int c    = idx / (2 * PERIOD * (FH / 4));
    int rem  = idx % (2 * PERIOD * (FH / 4));
    int w    = rem / (PERIOD * (FH / 4));
    int rem2 = rem % (PERIOD * (FH / 4));
    int p    = rem2 / (FH / 4);
    int fh4  = rem2 % (FH / 4);
    const float* W = w ? We2 : We1;
    int lbeg = c * (L_LEN / PCHUNK);
    int lend = lbeg + (L_LEN / PCHUNK);
    int l0   = lbeg + ((p - lbeg) % PERIOD + PERIOD) % PERIOD;
    f32x4 s = {0.f, 0.f, 0.f, 0.f};
    for (int l = l0; l < lend; l += PERIOD)
        s += *(const f32x4*)&W[(size_t)l * FH + fh4 * 4];
    *(f32x4*)&u4[(size_t)c * (2 * PERIOD * FH) + (size_t)w * PERIOD * FH + p * FH + fh4 * 4] = s;
}

// ---------------- kernel B2: fused 4-chunk reduce + slot tables (64 blocks) ----------------
__global__ void phase_tables(const float* __restrict__ u4, float* __restrict__ t1,
                             float* __restrict__ t2) {
    __shared__ f32x4 ul[2][PERIOD][TBF4];   // 6 KB
    int fb  = blockIdx.x * TBF4;            // fh4 base
    int tid = threadIdx.x;

    for (int e = tid; e < 2 * PERIOD * TBF4; e += 256) {
        int w  = e / (PERIOD * TBF4);
        int p  = (e / TBF4) % PERIOD;
        int f4 = e % TBF4;
        size_t base = (size_t)w * PERIOD * FH + (size_t)p * FH + (size_t)(fb + f4) * 4;
        f32x4 s = *(const f32x4*)&u4[base];
        #pragma unroll
        for (int c = 1; c < PCHUNK; ++c)
            s += *(const f32x4*)&u4[(size_t)c * (2 * PERIOD * FH) + base];
        ul[w][p][f4] = s;
    }
    __syncthreads();

    const float inv25 = 1.0f / 25.0f;
    for (int e = tid; e < NSLOT * TBF4; e += 256) {
        int s  = e / TBF4;
        int f4 = e % TBF4;
        f32x4 v1, v2;
        f32x4 mav1 = {0.f, 0.f, 0.f, 0.f}, mav2 = {0.f, 0.f, 0.f, 0.f};
        if (s < PERIOD) {                              // interior phase
            int p = s, pr = (p + THALF) % PERIOD;
            f32x4 Sv1 = {0.f, 0.f, 0.f, 0.f}, Sv2 = {0.f, 0.f, 0.f, 0.f};
            #pragma unroll
            for (int q = 0; q < PERIOD; ++q) {
                float cq = cinv(q);
                Sv1 += ul[0][q][f4] * cq;
                Sv2 += ul[1][q][f4] * cq;
            }
            v1 = ul[0][p][f4] * cinv(p);
            v2 = ul[1][p][f4] * cinv(p);
            mav1 = (Sv1 + ul[0][pr][f4] * cinv(pr)) * inv25;
            mav2 = (Sv2 + ul[1][pr][f4] * cinv(pr)) * inv25;
        } else {                                       // edge l, exact clipped window
            int e2 = s - PERIOD;
            int l  = (e2 < THALF) ? e2 : (L_LEN - THALF + (e2 - THALF));
            int pl = l % PERIOD;
            v1 = ul[0][pl][f4] * cinv(pl);
            v2 = ul[1][pl][f4] * cinv(pl);
            #pragma unroll
            for (int dl = -THALF; dl <= THALF; ++dl) {
                int j = l + dl;
                if (j >= 0 && j < L_LEN) {
                    int p = j % PERIOD;
                    float ci = cinv(p);
                    mav1 += ul[0][p][f4] * ci;
                    mav2 += ul[1][p][f4] * ci;
                }
            }
            mav1 *= inv25; mav2 *= inv25;
        }
        *(f32x4*)&t1[(size_t)s * FH + (size_t)(fb + f4) * 4] = v1 - mav1;
        *(f32x4*)&t2[(size_t)s * FH + (size_t)(fb + f4) * 4] = mav2 - v2;
    }
}

// ---------------- kernel C: build W' (bf16) — NLB=8, window regs + table lookups ----------------
__launch_bounds__(256, 3)
__global__ void build_wp(const float* __restrict__ We0, const float* __restrict__ We2,
                         const float* __restrict__ t1, const float* __restrict__ t2,
                         unsigned short* __restrict__ Wp) {
    __shared__ unsigned short tile[3][NLB][16][18];   // 13.8 KB
    int f  = threadIdx.x >> 4;
    int hl = threadIdx.x & 15;
    int h  = blockIdx.x * 16 + hl;
    int l0 = blockIdx.y * NLB;
    int fh = f * HDIM + h;

    float w0[NLB + 25], w2[NLB + 25];
    #pragma unroll
    for (int i = 0; i < NLB + 25; ++i) {
        int j = l0 - THALF + i;
        if (j >= 0 && j < L_LEN) {
            w0[i] = We0[(size_t)j * FH + fh];
            w2[i] = We2[(size_t)j * FH + fh];
        } else { w0[i] = 0.f; w2[i] = 0.f; }
    }

    float s0 = 0.f, s2 = 0.f;
    #pragma unroll
    for (int i = 0; i < 25; ++i) { s0 += w0[i]; s2 += w2[i]; }

    const float inv25 = 1.0f / 25.0f;
    #pragma unroll
    for (int r = 0; r < NLB; ++r) {
        int l = l0 + r;
        int slot = (l >= THALF && l < L_LEN - THALF)
                 ? (l % PERIOD)
                 : (PERIOD + ((l < THALF) ? l : (THALF + (l - (L_LEN - THALF)))));
        float tt1 = t1[(size_t)slot * FH + fh];
        float tt2 = t2[(size_t)slot * FH + fh];

        float out0 = s0 * inv25;                        // (T We0)[l]
        float out1 = tt1;                               // S^T We1
        float out2 = w2[r + THALF] - s2 * inv25 + tt2;  // (I-T-S)^T We2

        tile[0][r][hl][f] = f2bf(out0);
        tile[1][r][hl][f] = f2bf(out1);
        tile[2][r][hl][f] = f2bf(out2);

        s0 += w0[r + 25] - w0[r];                       // register-only slide
        s2 += w2[r + 25] - w2[r];
    }
    __syncthreads();

    {
        int cid = threadIdx.x;
        #pragma unroll
        for (int pass = 0; pass < 2; ++pass, cid += 256) {
            if (cid < 3 * 16 * NLB) {
                int m  = cid / (16 * NLB);
                int rm = cid % (16 * NLB);
                int h2 = rm / NLB;
                int ll = rm % NLB;
                const unsigned int* src = (const unsigned int*)&tile[m][ll][h2][0];
                union { unsigned int d[8]; bf16x16 v; } cvt;
                #pragma unroll
                for (int i = 0; i < 8; ++i) cvt.d[i] = src[i];
                *(bf16x16*)&Wp[(size_t)(m * HDIM + blockIdx.x * 16 + h2) * DDIM
                               + (size_t)(l0 + ll) * FDIM] = cvt.v;
            }
        }
    }
}

// ---------------- kernel D: part[z] = x @ Wp^T — BN=192 champion; bf16 partial stores ----------------
#define GBM 64
#define GBN 192
#define GBK 64
#define GSPLIT 16
#define GKSPL (DDIM / GSPLIT)    // 1024
#define GKST  (GKSPL / GBK)      // 16
#define LDA   72                 // A LDS stride: 144B ≡ 4 dwords mod 32 -> 2-way (free)
#define NWG2  (16 * 2 * GSPLIT)  // 512 blocks, %8==0 (bijective XCD swizzle)

__launch_bounds__(256, 2)
__global__ void gemm3(const float* __restrict__ x, const unsigned short* __restrict__ Wp,
                      unsigned short* __restrict__ part) {
    __shared__ unsigned short As[2][GBM * LDA];   // 2 x 9.2 KB
    __shared__ unsigned short Bs[2][GBN * GBK];   // 2 x 24 KB, linear dest, swizzled content
    int bid = blockIdx.x;
    int swz = (bid & 7) * (NWG2 / 8) + (bid >> 3);
    int bz  = swz / 32;            // 0..15
    int rem = swz % 32;
    int by  = rem / 16;            // 0..1
    int bx  = rem % 16;            // 0..15
    int m0 = bx * GBM, n0 = by * GBN, k0 = bz * GKSPL;
    int tid = threadIdx.x, lane = tid & 63, wave = tid >> 6;
    int wn = wave;                 // 4 waves: 1m x 4n, wave tile 64 x 48

    int arow = tid >> 2, aseg = tid & 3;
    const float* ag = x + (size_t)(m0 + arow) * DDIM + k0 + aseg * 16;
    int brc  = lane >> 3;                       // row within 8-row chunk
    int bsg  = (lane & 7) ^ brc;                // T2 source-pre-swizzle

    f32x4 Ra[4], Rb[4];
    f32x4 acc[4][3] = {};

    auto aload = [&](f32x4* R, int s) {
        const float* a = ag + s * GBK;
        #pragma unroll
        for (int i = 0; i < 4; ++i) R[i] = *(const f32x4*)(a + 4 * i);
    };
    auto astore = [&](const f32x4* R, int buf) {
        unsigned int w[8];
        #pragma unroll
        for (int t = 0; t < 8; ++t) {
            float lo = R[t >> 1][(t & 1) * 2];
            float hi = R[t >> 1][(t & 1) * 2 + 1];
            asm("v_cvt_pk_bf16_f32 %0, %1, %2" : "=v"(w[t]) : "v"(lo), "v"(hi));
        }
        unsigned short* dst = &As[buf][arow * LDA + aseg * 16];
        u32x4 v0 = {w[0], w[1], w[2], w[3]};
        u32x4 v1 = {w[4], w[5], w[6], w[7]};
        *(u32x4*)dst       = v0;
        *(u32x4*)(dst + 8) = v1;
    };
    auto bstage = [&](int buf, int s) {
        #pragma unroll
        for (int q = 0; q < 6; ++q) {
            int c = wave * 6 + q;                  // 8-row chunk id (0..23) -> 192 rows
            const unsigned short* g = Wp + (size_t)(n0 + c * 8 + brc) * DDIM
                                        + k0 + s * GBK + bsg * 8;
            __builtin_amdgcn_global_load_lds(
                (const __attribute__((address_space(1))) void*)g,
                (__attribute__((address_space(3))) void*)&Bs[buf][c * 512], 16, 0, 0);
        }
    };
    int frow = lane & 15, hi4 = lane >> 4;
    auto compute = [&](int buf) {
        #pragma unroll
        for (int ks = 0; ks < 2; ++ks) {
            bf16x8 av[4], bv[3];
            #pragma unroll
            for (int i = 0; i < 4; ++i)
                av[i] = *(const bf16x8*)&As[buf][(i*16 + frow) * LDA + ks*32 + hi4*8];
            #pragma unroll
            for (int j = 0; j < 3; ++j) {
                int rB = wn*48 + j*16 + frow;
                int sL = (ks*4 + hi4) ^ (frow & 7);    // un-swizzle on read
                bv[j] = *(const bf16x8*)&Bs[buf][rB * GBK + sL * 8];
            }
            #pragma unroll
            for (int i = 0; i < 4; ++i)
                #pragma unroll
                for (int j = 0; j < 3; ++j)
                    acc[i][j] = __builtin_amdgcn_mfma_f32_16x16x32_bf16(av[i], bv[j], acc[i][j], 0, 0, 0);
        }
    };

    // prologue: regs k0,k1; B0 DMA; A0 in LDS; barrier drains all
    aload(Ra, 0); aload(Rb, 1); bstage(0, 0); astore(Ra, 0);
    __syncthreads();

    for (int s2 = 0; s2 < GKST; s2 += 2) {
        {   int s = s2;                                  // even step, bufs 0
            if (s + 1 < GKST) bstage(1, s + 1);
            if (s + 2 < GKST) aload(Ra, s + 2);
            if (s + 1 < GKST) astore(Rb, 1);
            compute(0);
            __syncthreads();
        }
        {   int s = s2 + 1;                              // odd step, bufs 1
            if (s + 1 < GKST) bstage(0, s + 1);
            if (s + 2 < GKST) aload(Rb, s + 2);
            if (s + 1 < GKST) astore(Ra, 0);
            compute(1);
            __syncthreads();
        }
    }

    // epilogue: bf16 streaming stores to this k-split's private slab (half the bytes)
    unsigned short* pslab = part + (size_t)bz * (BATCH * NH3);
    int orow = (lane >> 4) * 4, ocol = lane & 15;   // C/D: col=lane&15, row=(lane>>4)*4+r
    #pragma unroll
    for (int i = 0; i < 4; ++i)
        #pragma unroll
        for (int j = 0; j < 3; ++j)
            #pragma unroll
            for (int r = 0; r < 4; ++r)
                pslab[(size_t)(m0 + i*16 + orow + r) * NH3
                      + (n0 + wn*48 + j*16 + ocol)] = f2bf(acc[i][j][r]);
}

// ---------------- kernel E: fused MLP tail — 4 rows/block, bf16 slab reads ----------------
__launch_bounds__(1024, 2)
__global__ void mlp_fused2(const unsigned short* __restrict__ part, const float* __restrict__ be0,
                           const float* __restrict__ be1, const float* __restrict__ be2,
                           const float* __restrict__ Wf1, const float* __restrict__ bf1,
                           const float* __restrict__ Wf2, const float* __restrict__ bf2,
                           float* __restrict__ out) {
    __shared__ float fr[4][NH3];        // 6 KB
    __shared__ float hp[8][4][HDIM];    // 16 KB
    __shared__ float hs[4][HDIM];       // 2 KB
    int b0 = blockIdx.x * 4, tid = threadIdx.x;

    for (int e = tid; e < 4 * NH3; e += 1024) {       // slab-reduce 4 rows
        int rr = e / NH3, cc = e % NH3;
        float v = (cc < HDIM) ? be0[cc]
                : (cc < 2*HDIM ? be1[cc - HDIM] : be2[cc - 2*HDIM]);
        #pragma unroll
        for (int z = 0; z < GSPLIT; ++z)              // 16 independent loads
            v += bf2f(part[(size_t)z * (BATCH * NH3) + (size_t)(b0 + rr) * NH3 + cc]);
        fr[rr][cc] = v;
    }
    __syncthreads();

    int j = tid & 127, c = tid >> 7;                  // c = 0..7, 48 i's each
    int i0 = c * 48;
    float a0 = 0.f, a1 = 0.f, a2 = 0.f, a3 = 0.f;     // 4 independent chains of 48
    #pragma unroll
    for (int k = 0; k < 48; ++k) {
        float w = Wf1[(size_t)(i0 + k) * HDIM + j];   // ONE load, FOUR fmas
        float f0 = fr[0][i0 + k], f1 = fr[1][i0 + k];
        float f2 = fr[2][i0 + k], f3 = fr[3][i0 + k];
        a0 = fmaf(f0, w, a0);
        a1 = fmaf(f1, w, a1);
        a2 = fmaf(f2, w, a2);
        a3 = fmaf(f3, w, a3);
    }
    hp[c][0][j] = a0; hp[c][1][j] = a1; hp[c][2][j] = a2; hp[c][3][j] = a3;
    __syncthreads();

    if (tid < 4 * HDIM) {
        int rr = tid >> 7, jj = tid & 127;
        float v = bf1[jj];
        #pragma unroll
        for (int cc = 0; cc < 8; ++cc) v += hp[cc][rr][jj];
        hs[rr][jj] = fmaxf(v, 0.f);
    }
    __syncthreads();

    int lane = tid & 63, wave = tid >> 6;             // 16 waves
    int rr = wave & 3, base = wave >> 2;              // wave -> (row, class-stride-4 set)
    #pragma unroll
    for (int cc = base; cc < NCLS; cc += 4) {
        float pp = hs[rr][lane] * Wf2[(size_t)lane * NCLS + cc];
        pp = fmaf(hs[rr][lane + 64], Wf2[(size_t)(lane + 64) * NCLS + cc], pp);
        #pragma unroll
        for (int off = 32; off; off >>= 1) pp += __shfl_down(pp, off);
        if (lane == 0) out[(size_t)(b0 + rr) * NCLS + cc] = pp + bf2[cc];
    }
}

extern "C" void kernel_launch(void* const* d_in, const int* in_sizes, int n_in,
                              void* d_out, int out_size, void* d_ws, size_t ws_size,
                              hipStream_t stream) {
    const float* x   = (const float*)d_in[0];
    const float* We0 = (const float*)d_in[1];
    const float* be0 = (const float*)d_in[2];
    const float* We1 = (const float*)d_in[3];
    const float* be1 = (const float*)d_in[4];
    const float* We2 = (const float*)d_in[5];
    const float* be2 = (const float*)d_in[6];
    const float* Wf1 = (const float*)d_in[7];
    const float* bf1 = (const float*)d_in[8];
    const float* Wf2 = (const float*)d_in[9];
    const float* bf2 = (const float*)d_in[10];
    float* out = (float*)d_out;

    char* wsb = (char*)d_ws;
    size_t off = 0;
    unsigned short* Wp = (unsigned short*)(wsb + off); off += (size_t)NH3 * DDIM * sizeof(unsigned short);   // 12.6 MB
    float* u4   = (float*)(wsb + off); off += (size_t)PCHUNK * 2 * PERIOD * FH * sizeof(float);              // 1.57 MB
    float* t1   = (float*)(wsb + off); off += (size_t)NSLOT * FH * sizeof(float);                            // 0.39 MB
    float* t2   = (float*)(wsb + off); off += (size_t)NSLOT * FH * sizeof(float);                            // 0.39 MB
    unsigned short* part = (unsigned short*)(wsb + off);
    off += (size_t)GSPLIT * BATCH * NH3 * sizeof(unsigned short);                                            // 12.6 MB

    phase_sums_part<<<(2 * PERIOD * (FH / 4) * PCHUNK + 255) / 256, 256, 0, stream>>>(We1, We2, u4);
    phase_tables<<<(FH / 4) / TBF4, 256, 0, stream>>>(u4, t1, t2);
    build_wp<<<dim3(8, L_LEN / NLB), 256, 0, stream>>>(We0, We2, t1, t2, Wp);
    gemm3<<<NWG2, 256, 0, stream>>>(x, Wp, part);
    mlp_fused2<<<BATCH / 4, 1024, 0, stream>>>(part, be0, be1, be2, Wf1, bf1, Wf2, bf2, out);
}

// Round 22
// 59.890 us; speedup vs baseline: 1.1544x; 1.0073x over previous
//
#include <hip/hip_runtime.h>

#define L_LEN  1024
#define FDIM   16
#define PERIOD 24
#define HDIM   128
#define BATCH  1024
#define DDIM   (L_LEN*FDIM)      // 16384
#define NH3    (3*HDIM)          // 384
#define THALF  12
#define NCLS   10
#define FH     (FDIM*HDIM)       // 2048
#define NLB    8                 // l-strip per build_wp block
#define PCHUNK 4                 // phase_sums l-chunks
#define NSLOT  48                // 24 interior phases + 24 edge l's
#define TBF4   8                 // fh4 columns per phase_tables block

typedef short bf16x8  __attribute__((ext_vector_type(8)));
typedef short bf16x16 __attribute__((ext_vector_type(16)));
typedef float f32x4   __attribute__((ext_vector_type(4)));
typedef unsigned int u32x4 __attribute__((ext_vector_type(4)));

__device__ __forceinline__ unsigned short f2bf(float f) {
    unsigned int u = __float_as_uint(f);
    u += 0x7FFFu + ((u >> 16) & 1u);           // RNE
    return (unsigned short)(u >> 16);
}
__device__ __forceinline__ float bf2f(unsigned short u) {
    return __uint_as_float((unsigned int)u << 16);
}
__device__ __forceinline__ float cinv(int p) { return (p < 16) ? (1.0f/43.0f) : (1.0f/42.0f); }

// ---------------- kernel B1: partial per-phase column sums (4 l-chunks, 384 blocks) ----------------
__global__ void phase_sums_part(const float* __restrict__ We1, const float* __restrict__ We2,
                                float* __restrict__ u4) {
    int idx = blockIdx.x * blockDim.x + threadIdx.x;
    if (idx >= 2 * PERIOD * (FH / 4) * PCHUNK) return;
    int c    = idx / (2 * PERIOD * (FH / 4));
    int rem  = idx % (2 * PERIOD * (FH / 4));
    int w    = rem / (PERIOD * (FH / 4));
    int rem2 = rem % (PERIOD * (FH / 4));
    int p    = rem2 / (FH / 4);
    int fh4  = rem2 % (FH / 4);
    const float* W = w ? We2 : We1;
    int lbeg = c * (L_LEN / PCHUNK);
    int lend = lbeg + (L_LEN / PCHUNK);
    int l0   = lbeg + ((p - lbeg) % PERIOD + PERIOD) % PERIOD;
    f32x4 s = {0.f, 0.f, 0.f, 0.f};
    for (int l = l0; l < lend; l += PERIOD)
        s += *(const f32x4*)&W[(size_t)l * FH + fh4 * 4];
    *(f32x4*)&u4[(size_t)c * (2 * PERIOD * FH) + (size_t)w * PERIOD * FH + p * FH + fh4 * 4] = s;
}

// ---------------- kernel B2: fused 4-chunk reduce + slot tables (64 blocks) ----------------
__global__ void phase_tables(const float* __restrict__ u4, float* __restrict__ t1,
                             float* __restrict__ t2) {
    __shared__ f32x4 ul[2][PERIOD][TBF4];   // 6 KB
    int fb  = blockIdx.x * TBF4;            // fh4 base
    int tid = threadIdx.x;

    for (int e = tid; e < 2 * PERIOD * TBF4; e += 256) {
        int w  = e / (PERIOD * TBF4);
        int p  = (e / TBF4) % PERIOD;
        int f4 = e % TBF4;
        size_t base = (size_t)w * PERIOD * FH + (size_t)p * FH + (size_t)(fb + f4) * 4;
        f32x4 s = *(const f32x4*)&u4[base];
        #pragma unroll
        for (int c = 1; c < PCHUNK; ++c)
            s += *(const f32x4*)&u4[(size_t)c * (2 * PERIOD * FH) + base];
        ul[w][p][f4] = s;
    }
    __syncthreads();

    const float inv25 = 1.0f / 25.0f;
    for (int e = tid; e < NSLOT * TBF4; e += 256) {
        int s  = e / TBF4;
        int f4 = e % TBF4;
        f32x4 v1, v2;
        f32x4 mav1 = {0.f, 0.f, 0.f, 0.f}, mav2 = {0.f, 0.f, 0.f, 0.f};
        if (s < PERIOD) {                              // interior phase
            int p = s, pr = (p + THALF) % PERIOD;
            f32x4 Sv1 = {0.f, 0.f, 0.f, 0.f}, Sv2 = {0.f, 0.f, 0.f, 0.f};
            #pragma unroll
            for (int q = 0; q < PERIOD; ++q) {
                float cq = cinv(q);
                Sv1 += ul[0][q][f4] * cq;
                Sv2 += ul[1][q][f4] * cq;
            }
            v1 = ul[0][p][f4] * cinv(p);
            v2 = ul[1][p][f4] * cinv(p);
            mav1 = (Sv1 + ul[0][pr][f4] * cinv(pr)) * inv25;
            mav2 = (Sv2 + ul[1][pr][f4] * cinv(pr)) * inv25;
        } else {                                       // edge l, exact clipped window
            int e2 = s - PERIOD;
            int l  = (e2 < THALF) ? e2 : (L_LEN - THALF + (e2 - THALF));
            int pl = l % PERIOD;
            v1 = ul[0][pl][f4] * cinv(pl);
            v2 = ul[1][pl][f4] * cinv(pl);
            #pragma unroll
            for (int dl = -THALF; dl <= THALF; ++dl) {
                int j = l + dl;
                if (j >= 0 && j < L_LEN) {
                    int p = j % PERIOD;
                    float ci = cinv(p);
                    mav1 += ul[0][p][f4] * ci;
                    mav2 += ul[1][p][f4] * ci;
                }
            }
            mav1 *= inv25; mav2 *= inv25;
        }
        *(f32x4*)&t1[(size_t)s * FH + (size_t)(fb + f4) * 4] = v1 - mav1;
        *(f32x4*)&t2[(size_t)s * FH + (size_t)(fb + f4) * 4] = mav2 - v2;
    }
}

// ---------------- kernel C: build W' (bf16) — NLB=8, window regs + table lookups ----------------
__launch_bounds__(256, 3)
__global__ void build_wp(const float* __restrict__ We0, const float* __restrict__ We2,
                         const float* __restrict__ t1, const float* __restrict__ t2,
                         unsigned short* __restrict__ Wp) {
    __shared__ unsigned short tile[3][NLB][16][18];   // 13.8 KB
    int f  = threadIdx.x >> 4;
    int hl = threadIdx.x & 15;
    int h  = blockIdx.x * 16 + hl;
    int l0 = blockIdx.y * NLB;
    int fh = f * HDIM + h;

    float w0[NLB + 25], w2[NLB + 25];
    #pragma unroll
    for (int i = 0; i < NLB + 25; ++i) {
        int j = l0 - THALF + i;
        if (j >= 0 && j < L_LEN) {
            w0[i] = We0[(size_t)j * FH + fh];
            w2[i] = We2[(size_t)j * FH + fh];
        } else { w0[i] = 0.f; w2[i] = 0.f; }
    }

    float s0 = 0.f, s2 = 0.f;
    #pragma unroll
    for (int i = 0; i < 25; ++i) { s0 += w0[i]; s2 += w2[i]; }

    const float inv25 = 1.0f / 25.0f;
    #pragma unroll
    for (int r = 0; r < NLB; ++r) {
        int l = l0 + r;
        int slot = (l >= THALF && l < L_LEN - THALF)
                 ? (l % PERIOD)
                 : (PERIOD + ((l < THALF) ? l : (THALF + (l - (L_LEN - THALF)))));
        float tt1 = t1[(size_t)slot * FH + fh];
        float tt2 = t2[(size_t)slot * FH + fh];

        float out0 = s0 * inv25;                        // (T We0)[l]
        float out1 = tt1;                               // S^T We1
        float out2 = w2[r + THALF] - s2 * inv25 + tt2;  // (I-T-S)^T We2

        tile[0][r][hl][f] = f2bf(out0);
        tile[1][r][hl][f] = f2bf(out1);
        tile[2][r][hl][f] = f2bf(out2);

        s0 += w0[r + 25] - w0[r];                       // register-only slide
        s2 += w2[r + 25] - w2[r];
    }
    __syncthreads();

    {
        int cid = threadIdx.x;
        #pragma unroll
        for (int pass = 0; pass < 2; ++pass, cid += 256) {
            if (cid < 3 * 16 * NLB) {
                int m  = cid / (16 * NLB);
                int rm = cid % (16 * NLB);
                int h2 = rm / NLB;
                int ll = rm % NLB;
                const unsigned int* src = (const unsigned int*)&tile[m][ll][h2][0];
                union { unsigned int d[8]; bf16x16 v; } cvt;
                #pragma unroll
                for (int i = 0; i < 8; ++i) cvt.d[i] = src[i];
                *(bf16x16*)&Wp[(size_t)(m * HDIM + blockIdx.x * 16 + h2) * DDIM
                               + (size_t)(l0 + ll) * FDIM] = cvt.v;
            }
        }
    }
}

// ---------------- kernel D: part[z] = x @ Wp^T — 64x192 tile, 8 waves (2m x 4n), bf16 stores ----------------
#define GBM 64
#define GBN 192
#define GBK 64
#define GSPLIT 16
#define GKSPL (DDIM / GSPLIT)    // 1024
#define GKST  (GKSPL / GBK)      // 16
#define LDA   72                 // A LDS stride: 144B ≡ 4 dwords mod 32 -> 2-way (free)
#define NWG2  (16 * 2 * GSPLIT)  // 512 blocks, %8==0 (bijective XCD swizzle)

__launch_bounds__(512, 2)
__global__ void gemm3(const float* __restrict__ x, const unsigned short* __restrict__ Wp,
                      unsigned short* __restrict__ part) {
    __shared__ unsigned short As[2][GBM * LDA];   // 2 x 9.2 KB
    __shared__ unsigned short Bs[2][GBN * GBK];   // 2 x 24 KB, linear dest, swizzled content
    int bid = blockIdx.x;
    int swz = (bid & 7) * (NWG2 / 8) + (bid >> 3);
    int bz  = swz / 32;            // 0..15
    int rem = swz % 32;
    int by  = rem / 16;            // 0..1
    int bx  = rem % 16;            // 0..15
    int m0 = bx * GBM, n0 = by * GBN, k0 = bz * GKSPL;
    int tid = threadIdx.x, lane = tid & 63, wave = tid >> 6;   // 8 waves
    int wm = wave >> 2, wn = wave & 3;                          // wave tile 32 x 48

    int arow = tid >> 3, aseg = tid & 7;        // A: 64 rows x 8 segs of 8 f32
    const float* ag = x + (size_t)(m0 + arow) * DDIM + k0 + aseg * 8;
    int brc  = lane >> 3;                       // row within 8-row chunk
    int bsg  = (lane & 7) ^ brc;                // T2 source-pre-swizzle

    f32x4 Ra[2], Rb[2];
    f32x4 acc[2][3] = {};

    auto aload = [&](f32x4* R, int s) {
        const float* a = ag + s * GBK;
        R[0] = *(const f32x4*)a;
        R[1] = *(const f32x4*)(a + 4);
    };
    auto astore = [&](const f32x4* R, int buf) {
        unsigned int w[4];
        #pragma unroll
        for (int t = 0; t < 4; ++t) {
            float lo = R[t >> 1][(t & 1) * 2];
            float hi = R[t >> 1][(t & 1) * 2 + 1];
            asm("v_cvt_pk_bf16_f32 %0, %1, %2" : "=v"(w[t]) : "v"(lo), "v"(hi));
        }
        u32x4 v0 = {w[0], w[1], w[2], w[3]};
        *(u32x4*)&As[buf][arow * LDA + aseg * 8] = v0;
    };
    auto bstage = [&](int buf, int s) {
        #pragma unroll
        for (int q = 0; q < 3; ++q) {
            int c = wave * 3 + q;                  // 8-row chunk id (0..23) -> 192 rows
            const unsigned short* g = Wp + (size_t)(n0 + c * 8 + brc) * DDIM
                                        + k0 + s * GBK + bsg * 8;
            __builtin_amdgcn_global_load_lds(
                (const __attribute__((address_space(1))) void*)g,
                (__attribute__((address_space(3))) void*)&Bs[buf][c * 512], 16, 0, 0);
        }
    };
    int frow = lane & 15, hi4 = lane >> 4;
    auto compute = [&](int buf) {
        #pragma unroll
        for (int ks = 0; ks < 2; ++ks) {
            bf16x8 av[2], bv[3];
            #pragma unroll
            for (int i = 0; i < 2; ++i)
                av[i] = *(const bf16x8*)&As[buf][(wm*32 + i*16 + frow) * LDA + ks*32 + hi4*8];
            #pragma unroll
            for (int j = 0; j < 3; ++j) {
                int rB = wn*48 + j*16 + frow;
                int sL = (ks*4 + hi4) ^ (frow & 7);    // un-swizzle on read
                bv[j] = *(const bf16x8*)&Bs[buf][rB * GBK + sL * 8];
            }
            #pragma unroll
            for (int i = 0; i < 2; ++i)
                #pragma unroll
                for (int j = 0; j < 3; ++j)
                    acc[i][j] = __builtin_amdgcn_mfma_f32_16x16x32_bf16(av[i], bv[j], acc[i][j], 0, 0, 0);
        }
    };

    // prologue: regs k0,k1; B0 DMA; A0 in LDS; barrier drains all
    aload(Ra, 0); aload(Rb, 1); bstage(0, 0); astore(Ra, 0);
    __syncthreads();

    for (int s2 = 0; s2 < GKST; s2 += 2) {
        {   int s = s2;                                  // even step, bufs 0
            if (s + 1 < GKST) bstage(1, s + 1);
            if (s + 2 < GKST) aload(Ra, s + 2);
            if (s + 1 < GKST) astore(Rb, 1);
            compute(0);
            __syncthreads();
        }
        {   int s = s2 + 1;                              // odd step, bufs 1
            if (s + 1 < GKST) bstage(0, s + 1);
            if (s + 2 < GKST) aload(Rb, s + 2);
            if (s + 1 < GKST) astore(Ra, 0);
            compute(1);
            __syncthreads();
        }
    }

    // epilogue: bf16 streaming stores to this k-split's private slab
    unsigned short* pslab = part + (size_t)bz * (BATCH * NH3);
    int orow = (lane >> 4) * 4, ocol = lane & 15;   // C/D: col=lane&15, row=(lane>>4)*4+r
    #pragma unroll
    for (int i = 0; i < 2; ++i)
        #pragma unroll
        for (int j = 0; j < 3; ++j)
            #pragma unroll
            for (int r = 0; r < 4; ++r)
                pslab[(size_t)(m0 + wm*32 + i*16 + orow + r) * NH3
                      + (n0 + wn*48 + j*16 + ocol)] = f2bf(acc[i][j][r]);
}

// ---------------- kernel E: fused MLP tail — 4 rows/block, bf16 slab reads (frozen) ----------------
__launch_bounds__(1024, 2)
__global__ void mlp_fused2(const unsigned short* __restrict__ part, const float* __restrict__ be0,
                           const float* __restrict__ be1, const float* __restrict__ be2,
                           const float* __restrict__ Wf1, const float* __restrict__ bf1,
                           const float* __restrict__ Wf2, const float* __restrict__ bf2,
                           float* __restrict__ out) {
    __shared__ float fr[4][NH3];        // 6 KB
    __shared__ float hp[8][4][HDIM];    // 16 KB
    __shared__ float hs[4][HDIM];       // 2 KB
    int b0 = blockIdx.x * 4, tid = threadIdx.x;

    for (int e = tid; e < 4 * NH3; e += 1024) {       // slab-reduce 4 rows
        int rr = e / NH3, cc = e % NH3;
        float v = (cc < HDIM) ? be0[cc]
                : (cc < 2*HDIM ? be1[cc - HDIM] : be2[cc - 2*HDIM]);
        #pragma unroll
        for (int z = 0; z < GSPLIT; ++z)              // 16 independent loads
            v += bf2f(part[(size_t)z * (BATCH * NH3) + (size_t)(b0 + rr) * NH3 + cc]);
        fr[rr][cc] = v;
    }
    __syncthreads();

    int j = tid & 127, c = tid >> 7;                  // c = 0..7, 48 i's each
    int i0 = c * 48;
    float a0 = 0.f, a1 = 0.f, a2 = 0.f, a3 = 0.f;     // 4 independent chains of 48
    #pragma unroll
    for (int k = 0; k < 48; ++k) {
        float w = Wf1[(size_t)(i0 + k) * HDIM + j];   // ONE load, FOUR fmas
        float f0 = fr[0][i0 + k], f1 = fr[1][i0 + k];
        float f2 = fr[2][i0 + k], f3 = fr[3][i0 + k];
        a0 = fmaf(f0, w, a0);
        a1 = fmaf(f1, w, a1);
        a2 = fmaf(f2, w, a2);
        a3 = fmaf(f3, w, a3);
    }
    hp[c][0][j] = a0; hp[c][1][j] = a1; hp[c][2][j] = a2; hp[c][3][j] = a3;
    __syncthreads();

    if (tid < 4 * HDIM) {
        int rr = tid >> 7, jj = tid & 127;
        float v = bf1[jj];
        #pragma unroll
        for (int cc = 0; cc < 8; ++cc) v += hp[cc][rr][jj];
        hs[rr][jj] = fmaxf(v, 0.f);
    }
    __syncthreads();

    int lane = tid & 63, wave = tid >> 6;             // 16 waves
    int rr = wave & 3, base = wave >> 2;              // wave -> (row, class-stride-4 set)
    #pragma unroll
    for (int cc = base; cc < NCLS; cc += 4) {
        float pp = hs[rr][lane] * Wf2[(size_t)lane * NCLS + cc];
        pp = fmaf(hs[rr][lane + 64], Wf2[(size_t)(lane + 64) * NCLS + cc], pp);
        #pragma unroll
        for (int off = 32; off; off >>= 1) pp += __shfl_down(pp, off);
        if (lane == 0) out[(size_t)(b0 + rr) * NCLS + cc] = pp + bf2[cc];
    }
}

extern "C" void kernel_launch(void* const* d_in, const int* in_sizes, int n_in,
                              void* d_out, int out_size, void* d_ws, size_t ws_size,
                              hipStream_t stream) {
    const float* x   = (const float*)d_in[0];
    const float* We0 = (const float*)d_in[1];
    const float* be0 = (const float*)d_in[2];
    const float* We1 = (const float*)d_in[3];
    const float* be1 = (const float*)d_in[4];
    const float* We2 = (const float*)d_in[5];
    const float* be2 = (const float*)d_in[6];
    const float* Wf1 = (const float*)d_in[7];
    const float* bf1 = (const float*)d_in[8];
    const float* Wf2 = (const float*)d_in[9];
    const float* bf2 = (const float*)d_in[10];
    float* out = (float*)d_out;

    char* wsb = (char*)d_ws;
    size_t off = 0;
    unsigned short* Wp = (unsigned short*)(wsb + off); off += (size_t)NH3 * DDIM * sizeof(unsigned short);   // 12.6 MB
    float* u4   = (float*)(wsb + off); off += (size_t)PCHUNK * 2 * PERIOD * FH * sizeof(float);              // 1.57 MB
    float* t1   = (float*)(wsb + off); off += (size_t)NSLOT * FH * sizeof(float);                            // 0.39 MB
    float* t2   = (float*)(wsb + off); off += (size_t)NSLOT * FH * sizeof(float);                            // 0.39 MB
    unsigned short* part = (unsigned short*)(wsb + off);
    off += (size_t)GSPLIT * BATCH * NH3 * sizeof(unsigned short);                                            // 12.6 MB

    phase_sums_part<<<(2 * PERIOD * (FH / 4) * PCHUNK + 255) / 256, 256, 0, stream>>>(We1, We2, u4);
    phase_tables<<<(FH / 4) / TBF4, 256, 0, stream>>>(u4, t1, t2);
    build_wp<<<dim3(8, L_LEN / NLB), 256, 0, stream>>>(We0, We2, t1, t2, Wp);
    gemm3<<<NWG2, 512, 0, stream>>>(x, Wp, part);
    mlp_fused2<<<BATCH / 4, 1024, 0, stream>>>(part, be0, be1, be2, Wf1, bf1, Wf2, bf2, out);
}